// Round 1
// baseline (33.003 us; speedup 1.0000x reference)
//
#include <hip/hip_runtime.h>
#include <math.h>

#define BN 4096
#define TILE 256

// ln(1e-4)
#define LOGE  (-9.210340371976184f)
#define EPSF  (1e-4f)
// sT = 2*eps*ln(eps), constant for every row
#define STC   (2.0f * EPSF * LOGE)

// ---------------- kernel 0: class counts ----------------
__global__ void k_counts(const int* __restrict__ tgt, int* __restrict__ counts) {
    __shared__ int sc[3];
    int tid = threadIdx.x;
    if (tid < 3) sc[tid] = 0;
    __syncthreads();
    int i = blockIdx.x * blockDim.x + tid;
    if (i < BN) atomicAdd(&sc[tgt[i]], 1);
    __syncthreads();
    if (tid < 3) atomicAdd(&counts[tid], sc[tid]);
}

// ---------------- kernel 1: per-row loss_0 and loss_2 ----------------
__global__ __launch_bounds__(256) void k_rows(const float* __restrict__ src,
                                              const int* __restrict__ tgt,
                                              const int* __restrict__ counts,
                                              double* __restrict__ acc) {
    int tid = threadIdx.x;
    int i = blockIdx.x * blockDim.x + tid;
    float c0 = 0.f, c2 = 0.f;
    {
        float x0 = src[3*i], x1 = src[3*i+1], x2 = src[3*i+2];
        float m  = fmaxf(x0, fmaxf(x1, x2));
        float e0 = expf(x0 - m), e1 = expf(x1 - m), e2 = expf(x2 - m);
        float s  = e0 + e1 + e2;
        float ls = logf(s);
        float L0 = x0 - m - ls, L1 = x1 - m - ls, L2 = x2 - m - ls;
        float sumLS = L0 + L1 + L2;
        int t = tgt[i];
        float LSt = (t == 0) ? L0 : ((t == 1) ? L1 : L2);
        // loss_0 contribution: -(T_i . LS_i)
        c0 = -(EPSF * sumLS + (1.0f - EPSF) * LSt);
        // loss_2: u_ik = eps*(2*loge - sumLS) + (1-eps)*(LT_i[k] - LS_i[k])
        float base = EPSF * (2.0f * LOGE - sumLS);
        float LT0 = (t == 0) ? 0.f : LOGE;
        float LT1 = (t == 1) ? 0.f : LOGE;
        float LT2 = (t == 2) ? 0.f : LOGE;
        float u0 = base + (1.0f - EPSF) * (LT0 - L0);
        float u1 = base + (1.0f - EPSF) * (LT1 - L1);
        float u2 = base + (1.0f - EPSF) * (LT2 - L2);
        c2 = (float)counts[0] * fabsf(u0) + (float)counts[1] * fabsf(u1)
           + (float)counts[2] * fabsf(u2);
    }
    __shared__ float r0[256], r2[256];
    r0[tid] = c0; r2[tid] = c2;
    __syncthreads();
    for (int s = 128; s > 0; s >>= 1) {
        if (tid < s) { r0[tid] += r0[tid + s]; r2[tid] += r2[tid + s]; }
        __syncthreads();
    }
    if (tid == 0) {
        atomicAdd(&acc[0], (double)r0[0]);
        atomicAdd(&acc[2], (double)r2[0]);
    }
}

// ---------------- kernel 2: B x B pair sums for loss_1, loss_3 ----------------
__global__ __launch_bounds__(256) void k_pairs(const float* __restrict__ src,
                                               const int* __restrict__ tgt,
                                               double* __restrict__ acc) {
    __shared__ float4 js[TILE];   // LS0, LS1, LS2, sumLS for j-row
    __shared__ int    jt[TILE];
    int tid = threadIdx.x;

    // cooperative: compute this block's j-tile row data
    {
        int j = blockIdx.y * TILE + tid;
        float x0 = src[3*j], x1 = src[3*j+1], x2 = src[3*j+2];
        float m  = fmaxf(x0, fmaxf(x1, x2));
        float e0 = expf(x0 - m), e1 = expf(x1 - m), e2 = expf(x2 - m);
        float s  = e0 + e1 + e2;
        float ls = logf(s);
        float L0 = x0 - m - ls, L1 = x1 - m - ls, L2 = x2 - m - ls;
        js[tid] = make_float4(L0, L1, L2, L0 + L1 + L2);
        jt[tid] = tgt[j];
    }
    __syncthreads();

    // this thread's i-row data
    int i = blockIdx.x * TILE + tid;
    float S0, S1, S2, aI;
    int ti;
    {
        float x0 = src[3*i], x1 = src[3*i+1], x2 = src[3*i+2];
        float m  = fmaxf(x0, fmaxf(x1, x2));
        float e0 = expf(x0 - m), e1 = expf(x1 - m), e2 = expf(x2 - m);
        float s  = e0 + e1 + e2;
        float inv = 1.0f / s;
        S0 = e0 * inv; S1 = e1 * inv; S2 = e2 * inv;
        float ls = logf(s);
        float L0 = x0 - m - ls, L1 = x1 - m - ls, L2 = x2 - m - ls;
        float sS = S0 * L0 + S1 * L1 + S2 * L2;
        ti = tgt[i];
        aI = sS - STC;                 // sS_i - sT
    }
    float tdSame = aI + 2.0f * EPSF * LOGE;     // + Tdot(ti==tj)
    float tdDiff = aI + (1.0f + EPSF) * LOGE;   // + Tdot(ti!=tj)

    float a1 = 0.f, a3 = 0.f;
    #pragma unroll 4
    for (int k = 0; k < TILE; ++k) {
        float4 L = js[k];              // broadcast read, conflict-free
        float d  = fmaf(S0, L.x, fmaf(S1, L.y, S2 * L.z));  // S_i . LS_j
        float e1v = fabsf(((jt[k] == ti) ? tdSame : tdDiff) - d);
        float LSt = (ti == 0) ? L.x : ((ti == 1) ? L.y : L.z);
        float tls = fmaf((1.0f - EPSF), LSt, EPSF * L.w);   // T_i . LS_j
        float e3v = fabsf(aI + tls - d);
        a1 += e1v; a3 += e3v;
    }

    __shared__ float r1[256], r3[256];
    r1[tid] = a1; r3[tid] = a3;
    __syncthreads();
    for (int s = 128; s > 0; s >>= 1) {
        if (tid < s) { r1[tid] += r1[tid + s]; r3[tid] += r3[tid + s]; }
        __syncthreads();
    }
    if (tid == 0) {
        atomicAdd(&acc[1], (double)r1[0]);
        atomicAdd(&acc[3], (double)r3[0]);
    }
}

// ---------------- kernel 3: finalize ----------------
__global__ void k_final(const double* __restrict__ acc, float* __restrict__ out) {
    if (threadIdx.x == 0 && blockIdx.x == 0) {
        double n2 = (double)BN * (double)BN;
        double l0 = acc[0] / (double)BN;
        double l1 = (1e-4 + acc[1]) / n2;
        double l2 = (1e-4 + acc[2]) / n2;
        double l3 = (1e-4 + acc[3]) / n2;
        out[0] = (float)((l0 + l1) + (l2 + l3));
        out[1] = (float)l0;
        out[2] = (float)l1;
        out[3] = (float)l2;
        out[4] = (float)l3;
    }
}

extern "C" void kernel_launch(void* const* d_in, const int* in_sizes, int n_in,
                              void* d_out, int out_size, void* d_ws, size_t ws_size,
                              hipStream_t stream) {
    const float* src = (const float*)d_in[0];
    const int*   tgt = (const int*)d_in[1];
    float*       out = (float*)d_out;
    double*      acc = (double*)d_ws;                 // 4 doubles
    int*      counts = (int*)((char*)d_ws + 32);      // 3 ints

    hipMemsetAsync(d_ws, 0, 64, stream);
    k_counts<<<BN / 256, 256, 0, stream>>>(tgt, counts);
    k_rows  <<<BN / 256, 256, 0, stream>>>(src, tgt, counts, acc);
    k_pairs <<<dim3(BN / TILE, BN / TILE), 256, 0, stream>>>(src, tgt, acc);
    k_final <<<1, 64, 0, stream>>>(acc, out);
}

// Round 2
// 16.489 us; speedup vs baseline: 2.0015x; 2.0015x over previous
//
#include <hip/hip_runtime.h>
#include <math.h>

#define BN   4096
#define GX   16          // i-tiles of 256 rows
#define GY   32          // j-tiles of 128 rows
#define TJ   128         // j-tile size
#define NB   (GX * GY)   // 512 partial slots

// ln(1e-4)
#define LOGE  (-9.210340371976184f)
#define EPSF  (1e-4f)
// sT = 2*eps*ln(eps), constant for every row
#define STC   (2.0f * EPSF * LOGE)

// ---------------- kernel 1: fused counts/rows/pairs -> per-block partials ----
// partial[bid*4 + {0,1,2,3}] = {a1, a3, c2, c0} block partial sums
__global__ __launch_bounds__(256) void k_pairs(const float* __restrict__ src,
                                               const int* __restrict__ tgt,
                                               float* __restrict__ partial) {
    __shared__ float4 js[TJ];     // LS0, LS1, LS2, (float)class  for j-row
    __shared__ int    sc[3];      // j-tile class counts
    int tid = threadIdx.x;
    int bx = blockIdx.x, by = blockIdx.y;

    if (tid < 3) sc[tid] = 0;

    // ---- this thread's i-row data (registers only) ----
    int i = bx * 256 + tid;
    float S0, S1, S2, aI, sumLS_i, L0i, L1i, L2i;
    int ti;
    {
        float x0 = src[3*i], x1 = src[3*i+1], x2 = src[3*i+2];
        float m  = fmaxf(x0, fmaxf(x1, x2));
        float e0 = expf(x0 - m), e1 = expf(x1 - m), e2 = expf(x2 - m);
        float s  = e0 + e1 + e2;
        float inv = 1.0f / s;
        S0 = e0 * inv; S1 = e1 * inv; S2 = e2 * inv;
        float ls = logf(s);
        L0i = x0 - m - ls; L1i = x1 - m - ls; L2i = x2 - m - ls;
        sumLS_i = L0i + L1i + L2i;
        float sS = S0 * L0i + S1 * L1i + S2 * L2i;
        ti = tgt[i];
        aI = sS - STC;                 // sS_i - sT
    }
    float tif = (float)ti;
    // T_i . LT_j  additions to aI, by class match
    float tdSame = aI + 2.0f * EPSF * LOGE;
    float tdDiff = aI + (1.0f + EPSF) * LOGE;
    // weight vector for T_i . LS_j = w . LS_j
    float w0 = EPSF + ((ti == 0) ? (1.0f - EPSF) : 0.0f);
    float w1 = EPSF + ((ti == 1) ? (1.0f - EPSF) : 0.0f);
    float w2 = EPSF + ((ti == 2) ? (1.0f - EPSF) : 0.0f);
    // loss_2 per-class |u_ik|
    float base = EPSF * (2.0f * LOGE - sumLS_i);
    float au0 = fabsf(base + (1.0f - EPSF) * (((ti == 0) ? 0.f : LOGE) - L0i));
    float au1 = fabsf(base + (1.0f - EPSF) * (((ti == 1) ? 0.f : LOGE) - L1i));
    float au2 = fabsf(base + (1.0f - EPSF) * (((ti == 2) ? 0.f : LOGE) - L2i));
    // loss_0 per-row (counted once: only by==0 blocks)
    float LSt = (ti == 0) ? L0i : ((ti == 1) ? L1i : L2i);
    float c0 = (by == 0) ? -(EPSF * sumLS_i + (1.0f - EPSF) * LSt) : 0.0f;

    __syncthreads();   // sc zeroed

    // ---- stage j-tile into LDS ----
    if (tid < TJ) {
        int j = by * TJ + tid;
        float x0 = src[3*j], x1 = src[3*j+1], x2 = src[3*j+2];
        float m  = fmaxf(x0, fmaxf(x1, x2));
        float e0 = expf(x0 - m), e1 = expf(x1 - m), e2 = expf(x2 - m);
        float s  = e0 + e1 + e2;
        float ls = logf(s);
        int tj = tgt[j];
        js[tid] = make_float4(x0 - m - ls, x1 - m - ls, x2 - m - ls, (float)tj);
        atomicAdd(&sc[tj], 1);
    }
    __syncthreads();

    // loss_2 contribution: local j-tile counts x per-class |u|
    float c2 = (float)sc[0] * au0 + (float)sc[1] * au1 + (float)sc[2] * au2;

    // ---- pair loop over j-tile ----
    float a1 = 0.f, a3 = 0.f;
    #pragma unroll 4
    for (int k = 0; k < TJ; ++k) {
        float4 L = js[k];                                   // broadcast, conflict-free
        float d   = fmaf(S0, L.x, fmaf(S1, L.y, S2 * L.z)); // S_i . LS_j
        float tls = fmaf(w0, L.x, fmaf(w1, L.y, w2 * L.z)); // T_i . LS_j
        float td  = (L.w == tif) ? tdSame : tdDiff;
        a1 += fabsf(td - d);
        a3 += fabsf(aI + tls - d);
    }

    // ---- block reduction of (a1, a3, c2, c0) ----
    __shared__ float r1[256], r3[256], r2[256], r0[256];
    r1[tid] = a1; r3[tid] = a3; r2[tid] = c2; r0[tid] = c0;
    __syncthreads();
    for (int s = 128; s > 0; s >>= 1) {
        if (tid < s) {
            r1[tid] += r1[tid + s]; r3[tid] += r3[tid + s];
            r2[tid] += r2[tid + s]; r0[tid] += r0[tid + s];
        }
        __syncthreads();
    }
    if (tid == 0) {
        int bid = by * GX + bx;
        float4 p = make_float4(r1[0], r3[0], r2[0], r0[0]);
        *reinterpret_cast<float4*>(partial + bid * 4) = p;
    }
}

// ---------------- kernel 2: reduce partials, finalize ----------------
__global__ __launch_bounds__(512) void k_final(const float* __restrict__ partial,
                                               float* __restrict__ out) {
    __shared__ double s1[512], s3[512], s2[512], s0[512];
    int tid = threadIdx.x;
    float4 p = *reinterpret_cast<const float4*>(partial + tid * 4);
    s1[tid] = (double)p.x; s3[tid] = (double)p.y;
    s2[tid] = (double)p.z; s0[tid] = (double)p.w;
    __syncthreads();
    for (int s = 256; s > 0; s >>= 1) {
        if (tid < s) {
            s1[tid] += s1[tid + s]; s3[tid] += s3[tid + s];
            s2[tid] += s2[tid + s]; s0[tid] += s0[tid + s];
        }
        __syncthreads();
    }
    if (tid == 0) {
        double n2 = (double)BN * (double)BN;
        double l0 = s0[0] / (double)BN;
        double l1 = (1e-4 + s1[0]) / n2;
        double l2 = (1e-4 + s2[0]) / n2;
        double l3 = (1e-4 + s3[0]) / n2;
        out[0] = (float)((l0 + l1) + (l2 + l3));
        out[1] = (float)l0;
        out[2] = (float)l1;
        out[3] = (float)l2;
        out[4] = (float)l3;
    }
}

extern "C" void kernel_launch(void* const* d_in, const int* in_sizes, int n_in,
                              void* d_out, int out_size, void* d_ws, size_t ws_size,
                              hipStream_t stream) {
    const float* src = (const float*)d_in[0];
    const int*   tgt = (const int*)d_in[1];
    float*       out = (float*)d_out;
    float*   partial = (float*)d_ws;    // NB*4 floats, fully rewritten every call

    k_pairs<<<dim3(GX, GY), 256, 0, stream>>>(src, tgt, partial);
    k_final<<<1, 512, 0, stream>>>(partial, out);
}